// Round 8
// baseline (119.178 us; speedup 1.0000x reference)
//
#include <hip/hip_runtime.h>
#include <hip/hip_bf16.h>
#include <string.h>

constexpr int B_ = 8;
constexpr int N_ = 2048;
constexpr int FIN = 128;
constexpr int FOUT = 64;
constexpr float ALPHA_ = 0.2f;
constexpr float NEG_INF_ = -9000000000000000.0f;

typedef __attribute__((ext_vector_type(8))) short bf16x8;
typedef __attribute__((ext_vector_type(4))) float f32x4;

static __device__ __forceinline__ unsigned short f2bf(float x) {
  unsigned int u = __float_as_uint(x);
  unsigned int r = u + 0x7fffu + ((u >> 16) & 1u);
  return (unsigned short)(r >> 16);
}

// ---------------- Kernel 1: Wh^T (bf16) + si/sj (f32, exact) ----------------
__global__ __launch_bounds__(256) void k_wh(
    const float* __restrict__ h, const float* __restrict__ W,
    const float* __restrict__ a, unsigned short* __restrict__ WhT,
    float* __restrict__ si, float* __restrict__ sj) {
  const int lane = threadIdx.x & 63;
  const int wv = threadIdx.x >> 6;
  const int grow0 = blockIdx.x * 32 + wv * 8;  // b*N + n, 8 rows
  const int f = lane;
  float acc[8] = {0.f, 0.f, 0.f, 0.f, 0.f, 0.f, 0.f, 0.f};
  const float* hp = h + (size_t)grow0 * FIN;
#pragma unroll 4
  for (int k = 0; k < FIN; k += 4) {
    float w0 = W[k * FOUT + f];
    float w1 = W[(k + 1) * FOUT + f];
    float w2 = W[(k + 2) * FOUT + f];
    float w3 = W[(k + 3) * FOUT + f];
#pragma unroll
    for (int r = 0; r < 8; ++r) {
      float4 hv = *(const float4*)(hp + r * FIN + k);
      acc[r] = fmaf(hv.x, w0, acc[r]);
      acc[r] = fmaf(hv.y, w1, acc[r]);
      acc[r] = fmaf(hv.z, w2, acc[r]);
      acc[r] = fmaf(hv.w, w3, acc[r]);
    }
  }
  const float a1 = a[f], a2 = a[FOUT + f];
#pragma unroll
  for (int r = 0; r < 8; ++r) {
    float p1 = acc[r] * a1;
    float p2 = acc[r] * a2;
#pragma unroll
    for (int off = 32; off; off >>= 1) {
      p1 += __shfl_xor(p1, off);
      p2 += __shfl_xor(p2, off);
    }
    if (lane == 0) {
      si[grow0 + r] = p1;
      sj[grow0 + r] = p2;
    }
  }
  const int b = grow0 >> 11;
  const int n0 = grow0 & (N_ - 1);
  __align__(16) unsigned short u[8];
#pragma unroll
  for (int r = 0; r < 8; ++r) u[r] = f2bf(acc[r]);
  *(bf16x8*)&WhT[(((size_t)(b * FOUT + f)) << 11) + n0] = *(const bf16x8*)u;
}

// ---------------- Kernel 2: adj -> bitmasks ----------------
__global__ __launch_bounds__(256) void k_pack(
    const int* __restrict__ adj, unsigned long long* __restrict__ mask_rm,
    unsigned int* __restrict__ mask_t) {
  const int lane = threadIdx.x & 63;
  const int wv = threadIdx.x >> 6;
  const int r = blockIdx.x * 4 + wv;
  const int* row = adj + (size_t)r * N_;
  unsigned int wacc = 0;
#pragma unroll
  for (int it = 0; it < 32; ++it) {
    int v = row[it * 64 + lane];
    unsigned long long bm = __ballot(v > 0);
    if (lane == 0) mask_rm[r * 32 + it] = bm;
    wacc |= ((unsigned int)(v > 0)) << it;
  }
  mask_t[r * 64 + lane] = wacc;
}

// ---------------- Kernel 3: per-row softmax stats ----------------
__global__ __launch_bounds__(256) void k_stats(
    const unsigned int* __restrict__ mask_t, const float* __restrict__ si,
    const float* __restrict__ sj, float* __restrict__ mrow,
    float* __restrict__ rrow) {
  const int lane = threadIdx.x & 63;
  const int wv = threadIdx.x >> 6;
  const int row = blockIdx.x * 4 + wv;  // b*N + i
  const int b = row >> 11;
  const int i = row & (N_ - 1);
  const unsigned int w32 = mask_t[i * 64 + lane];
  const float* sjb = sj + ((size_t)b << 11);
  float sjv[32];
  float M = -3.0e38f;
#pragma unroll
  for (int it = 0; it < 32; ++it) {
    sjv[it] = sjb[it * 64 + lane];
    if ((w32 >> it) & 1u) M = fmaxf(M, sjv[it]);
  }
#pragma unroll
  for (int off = 32; off; off >>= 1) M = fmaxf(M, __shfl_xor(M, off));
  const float siv = si[row];
  const float e0 = siv + M;
  const float m = e0 > 0.f ? e0 : ALPHA_ * e0;
  float s = 0.f;
#pragma unroll
  for (int it = 0; it < 32; ++it) {
    float e = siv + sjv[it];
    float v = e > 0.f ? e : ALPHA_ * e;
    float p = __expf(v - m);
    s += ((w32 >> it) & 1u) ? p : 0.f;
  }
#pragma unroll
  for (int off = 32; off; off >>= 1) s += __shfl_xor(s, off);
  if (lane == 0) {
    mrow[row] = m;
    rrow[row] = 1.f / s;
  }
}

// ---------------- Kernel 4: pure attention writer (fill-shaped) -------------
// One wave per att row; per iter a wave stores 1 KB fully packed.
__global__ __launch_bounds__(256) void k_att(
    const unsigned char* __restrict__ maskb, const float* __restrict__ si,
    const float* __restrict__ sjg, const float* __restrict__ mrow,
    const float* __restrict__ rrow, float* __restrict__ att_out) {
  const int lane = threadIdx.x & 63;
  const int wv = threadIdx.x >> 6;
  const int row = blockIdx.x * 4 + wv;  // b*N + i
  const int b = row >> 11;
  const int i = row & (N_ - 1);
  const float sir = si[row];
  const float mK = mrow[row] * 1.44269504f;
  const float rr = rrow[row];
  const float* __restrict__ sjb = sjg + ((size_t)b << 11);
  const unsigned char* __restrict__ mb = maskb + i * 256;
  float* __restrict__ ao = att_out + ((size_t)row << 11);

#pragma unroll
  for (int it = 0; it < 8; ++it) {
    const int j = it * 256 + lane * 4;
    const float4 s = *(const float4*)(sjb + j);
    const unsigned int mby = mb[it * 32 + (lane >> 1)] >> ((lane & 1) * 4);
    const float sjl[4] = {s.x, s.y, s.z, s.w};
    float av[4];
#pragma unroll
    for (int e = 0; e < 4; ++e) {
      float ev = sir + sjl[e];
      float v = fmaxf(ev, ALPHA_ * ev);
      float p = exp2f(fmaf(v, 1.44269504f, -mK)) * rr;
      av[e] = ((mby >> e) & 1u) ? p : 0.f;
    }
    f32x4 vv = {av[0], av[1], av[2], av[3]};
    *(f32x4*)(ao + j) = vv;
  }
}

// ---------------- Kernel 5: h' = att @ Wh, reading att back ------------------
// Block: 32 rows x 64 cols of one batch, 512 threads (8 waves).
// Wave (rt = wv>>2, kw = wv&3): row-tile rt, K-quarter kw (512 k's, 16 steps).
// A: contiguous f32x8 per lane from att_out (full 128-B line per row per step),
// cvt to bf16 in-reg. B: bf16x8 direct from L2-resident WhT. 16 KB LDS reduce.
__global__ __launch_bounds__(512, 4) void k_gemm(
    const float* __restrict__ att, const unsigned short* __restrict__ WhT,
    float* __restrict__ h_out) {
  __shared__ float red[4][16][FOUT];  // 16 KB

  const int bid = blockIdx.x;  // 512
  const int swz = (bid & 7) * 64 + (bid >> 3);  // XCD <-> batch
  const int b = swz >> 6;
  const int i0 = (swz & 63) * 32;

  const int tid = threadIdx.x;
  const int lane = tid & 63;
  const int wv = tid >> 6;
  const int rt = wv >> 2;  // 0..1
  const int kw = wv & 3;   // 0..3 K-quarter
  const int rl = lane & 15;
  const int hi = lane >> 4;

  const float* __restrict__ arow =
      att + (((size_t)((b << 11) + i0 + rt * 16 + rl)) << 11) + kw * 512 + hi * 8;
  const unsigned short* wb[4];
#pragma unroll
  for (int ct = 0; ct < 4; ++ct)
    wb[ct] = WhT + (((size_t)(b * FOUT + ct * 16 + rl)) << 11) + kw * 512 + hi * 8;

  f32x4 acc[4];
#pragma unroll
  for (int ct = 0; ct < 4; ++ct) acc[ct] = (f32x4){0.f, 0.f, 0.f, 0.f};

#pragma unroll 4
  for (int ks = 0; ks < 16; ++ks) {
    const float4 a0 = *(const float4*)(arow + ks * 32);
    const float4 a1 = *(const float4*)(arow + ks * 32 + 4);
    __align__(16) unsigned short u[8];
    u[0] = f2bf(a0.x); u[1] = f2bf(a0.y); u[2] = f2bf(a0.z); u[3] = f2bf(a0.w);
    u[4] = f2bf(a1.x); u[5] = f2bf(a1.y); u[6] = f2bf(a1.z); u[7] = f2bf(a1.w);
    const bf16x8 af = *(const bf16x8*)u;
#pragma unroll
    for (int ct = 0; ct < 4; ++ct) {
      bf16x8 bv = *(const bf16x8*)(wb[ct] + ks * 32);
      acc[ct] = __builtin_amdgcn_mfma_f32_16x16x32_bf16(af, bv, acc[ct], 0, 0, 0);
    }
  }

  // reduce the 4 K-quarters per row-tile. C layout: row=hi*4+rg, col=ct*16+rl.
  if (kw < 2) {
#pragma unroll
    for (int ct = 0; ct < 4; ++ct)
#pragma unroll
      for (int rg = 0; rg < 4; ++rg)
        red[rt * 2 + kw][hi * 4 + rg][ct * 16 + rl] = acc[ct][rg];
  }
  __syncthreads();
  if (kw >= 2) {
#pragma unroll
    for (int ct = 0; ct < 4; ++ct)
#pragma unroll
      for (int rg = 0; rg < 4; ++rg)
        red[rt * 2 + (kw - 2)][hi * 4 + rg][ct * 16 + rl] += acc[ct][rg];
  }
  __syncthreads();

#pragma unroll
  for (int k = tid; k < 32 * FOUT; k += 512) {
    const int r = k >> 6;   // 0..31
    const int c = k & 63;
    const int rt2 = r >> 4;
    const int rr2 = r & 15;
    float x = red[rt2 * 2][rr2][c] + red[rt2 * 2 + 1][rr2][c];
    float o = x > 0.f ? x : __expf(x) - 1.f;
    h_out[(((size_t)((b << 11) + i0 + r)) << 6) + c] = o;
  }
}

extern "C" void kernel_launch(void* const* d_in, const int* in_sizes, int n_in,
                              void* d_out, int out_size, void* d_ws, size_t ws_size,
                              hipStream_t stream) {
  const float* h = (const float*)d_in[0];
  const int* adj = (const int*)d_in[1];
  const float* W = (const float*)d_in[2];
  const float* a = (const float*)d_in[3];

  float* out = (float*)d_out;
  float* h_out = out;                             // B*N*FOUT
  float* att_out = out + (size_t)B_ * N_ * FOUT;  // B*N*N

  unsigned short* WhT = (unsigned short*)d_ws;                       // 2 MB
  float* si = (float*)((char*)d_ws + (size_t)2 * 1024 * 1024);       // 64 KB
  float* sj = si + B_ * N_;                                          // 64 KB
  float* mrow = sj + B_ * N_;                                        // 64 KB
  float* rrow = mrow + B_ * N_;                                      // 64 KB
  unsigned long long* mask_rm = (unsigned long long*)(rrow + B_ * N_);  // 512 KB
  unsigned int* mask_t = (unsigned int*)((char*)mask_rm + (size_t)N_ * 32 * 8);  // 512 KB

  k_wh<<<B_ * N_ / 32, 256, 0, stream>>>(h, W, a, WhT, si, sj);
  k_pack<<<N_ / 4, 256, 0, stream>>>(adj, mask_rm, mask_t);
  k_stats<<<B_ * N_ / 4, 256, 0, stream>>>(mask_t, si, sj, mrow, rrow);
  k_att<<<B_ * N_ / 4, 256, 0, stream>>>((const unsigned char*)mask_rm, si, sj,
                                         mrow, rrow, att_out);
  k_gemm<<<B_ * (N_ / 32), 512, 0, stream>>>(att_out, WhT, h_out);
}